// Round 1
// 109.983 us; speedup vs baseline: 1.0119x; 1.0119x over previous
//
#include <hip/hip_runtime.h>

#define N_NODES 256
#define F_DIM   16
#define H_DIM   2048
#define P_DIM   16
#define E_EDGES 32768
#define BLK     512

// ---------------------------------------------------------------------------
// Algebra: out = A@(x@W)+b re-associated as (A@x)@W+b (K: 2048 -> 16), with
//   A[d][s] = dinv[d]*dinv[s]*(cnt[d][s] + [s==d]), dinv = rsqrt(indeg+1).
//   g[n][f] = dinv[n] * sum_s (cnt[n][s] + [s==n]) * dinv[s] * x[s][f]
//   o[n][h] = sum_f g[n][f] W[f][h] + b[h];  q[n][p] = sum_h o[n][h] Wq[n][h][p] + bq[n][p]
// ws: cnt[d*256+s] 65536 floats (dst-major -> block n reads ROW n coalesced),
//     deg[256] floats built edge-parallel (kills the per-block 256KB colsum).
// ---------------------------------------------------------------------------

// K1: edge-parallel count + degree build. cnt: 65536 addrs, ~0.5 edges each.
// deg: 256 addrs, ~128 edges each — L2 atomics, measured-cheap vs the 64 MB
// of colsum reads it replaces.
__global__ __launch_bounds__(256) void k_cnt(const int* __restrict__ ei,
                                             float* __restrict__ cnt,
                                             float* __restrict__ deg) {
    int e = blockIdx.x * 256 + threadIdx.x;     // covers 32768 exactly
    int s = ei[e];
    int d = ei[E_EDGES + e];
    atomicAdd(&cnt[d * N_NODES + s], 1.0f);
    atomicAdd(&deg[d], 1.0f);
}

// K2: one block per node, 512 threads (2 waves/SIMD for stream MLP).
// g built register-only: threads 0..255 own source s=t, __shfl_xor butterfly,
// cross-wave combine via 256B LDS. No LDS atomics, no cntT re-scan.
__global__ __launch_bounds__(BLK) void k_node(
    const float* __restrict__ cnt, const float* __restrict__ deg,
    const float* __restrict__ x,   const float* __restrict__ W,
    const float* __restrict__ b,   const float* __restrict__ Wq,
    const float* __restrict__ bq,  float* __restrict__ qout)
{
    __shared__ float gw[4][F_DIM];
    __shared__ float gfin[F_DIM];
    __shared__ float red[BLK / 64][P_DIM];

    const int n = blockIdx.x;
    const int t = threadIdx.x;
    const int w = t >> 6, l = t & 63;

    // ---- issue the full Wq stream first (independent of all compute):
    // 16 float4/thread, HBM/L3 latency hides under g-phase + W matvec.
    const float4* Wqn = (const float4*)(Wq + (size_t)n * (H_DIM * P_DIM));
    float4 u00, u01, u02, u03, u10, u11, u12, u13;
    float4 u20, u21, u22, u23, u30, u31, u32, u33;
    {
        int h0 = (t          ) * 4;
        int h1 = (t +     BLK) * 4;
        int h2 = (t + 2 * BLK) * 4;
        int h3 = (t + 3 * BLK) * 4;
        u00 = Wqn[h0 + 0]; u01 = Wqn[h0 + 1]; u02 = Wqn[h0 + 2]; u03 = Wqn[h0 + 3];
        u10 = Wqn[h1 + 0]; u11 = Wqn[h1 + 1]; u12 = Wqn[h1 + 2]; u13 = Wqn[h1 + 3];
        u20 = Wqn[h2 + 0]; u21 = Wqn[h2 + 1]; u22 = Wqn[h2 + 2]; u23 = Wqn[h2 + 3];
        u30 = Wqn[h3 + 0]; u31 = Wqn[h3 + 1]; u32 = Wqn[h3 + 2]; u33 = Wqn[h3 + 3];
    }

    float dn = rsqrtf(deg[n] + 1.0f);    // broadcast load, all threads

    // ---- g-phase: waves 0..3 only (full waves, shfl-safe)
    if (t < N_NODES) {
        float dt = rsqrtf(deg[t] + 1.0f);
        float a  = (cnt[n * N_NODES + t] + (t == n ? 1.0f : 0.0f)) * dt;
        const float4* x4 = (const float4*)(x + t * F_DIM);
        float4 a0 = x4[0], a1 = x4[1], a2 = x4[2], a3 = x4[3];
        float val[F_DIM];
        val[0]  = a * a0.x; val[1]  = a * a0.y; val[2]  = a * a0.z; val[3]  = a * a0.w;
        val[4]  = a * a1.x; val[5]  = a * a1.y; val[6]  = a * a1.z; val[7]  = a * a1.w;
        val[8]  = a * a2.x; val[9]  = a * a2.y; val[10] = a * a2.z; val[11] = a * a2.w;
        val[12] = a * a3.x; val[13] = a * a3.y; val[14] = a * a3.z; val[15] = a * a3.w;
#pragma unroll
        for (int f = 0; f < F_DIM; ++f)
#pragma unroll
            for (int off = 32; off > 0; off >>= 1)
                val[f] += __shfl_xor(val[f], off, 64);
        if (l == 0) {
#pragma unroll
            for (int f = 0; f < F_DIM; ++f) gw[w][f] = val[f];
        }
    }
    __syncthreads();
    if (t < F_DIM)
        gfin[t] = gw[0][t] + gw[1][t] + gw[2][t] + gw[3][t];
    __syncthreads();

    float gr[F_DIM];
#pragma unroll
    for (int f = 0; f < F_DIM; ++f) gr[f] = gfin[f] * dn;   // broadcast reads

    // ---- o[i] = b[hh] + sum_f gr[f]*W[f][hh], hh = t + 512*i (coalesced, L2)
    float o[4];
#pragma unroll
    for (int i = 0; i < 4; ++i) {
        int hh = t + BLK * i;
        float v = b[hh];
#pragma unroll
        for (int f = 0; f < F_DIM; ++f)
            v += gr[f] * W[f * H_DIM + hh];
        o[i] = v;
    }

    // ---- acc[p] += o * Wq (data already in flight/registers)
    float acc[16];
#pragma unroll
    for (int p = 0; p < 16; ++p) acc[p] = 0.0f;

#define ACC4(OV, U0, U1, U2, U3) { float ov = (OV);                            \
    acc[0]  += ov * U0.x; acc[1]  += ov * U0.y; acc[2]  += ov * U0.z; acc[3]  += ov * U0.w; \
    acc[4]  += ov * U1.x; acc[5]  += ov * U1.y; acc[6]  += ov * U1.z; acc[7]  += ov * U1.w; \
    acc[8]  += ov * U2.x; acc[9]  += ov * U2.y; acc[10] += ov * U2.z; acc[11] += ov * U2.w; \
    acc[12] += ov * U3.x; acc[13] += ov * U3.y; acc[14] += ov * U3.z; acc[15] += ov * U3.w; }

    ACC4(o[0], u00, u01, u02, u03)
    ACC4(o[1], u10, u11, u12, u13)
    ACC4(o[2], u20, u21, u22, u23)
    ACC4(o[3], u30, u31, u32, u33)
#undef ACC4

    // ---- wave butterfly then cross-wave via LDS
#pragma unroll
    for (int p = 0; p < 16; ++p)
#pragma unroll
        for (int off = 32; off > 0; off >>= 1)
            acc[p] += __shfl_down(acc[p], off, 64);

    if (l == 0) {
#pragma unroll
        for (int p = 0; p < 16; ++p) red[w][p] = acc[p];
    }
    __syncthreads();
    if (t < P_DIM) {
        float s = bq[n * P_DIM + t];
#pragma unroll
        for (int ww = 0; ww < BLK / 64; ++ww) s += red[ww][t];
        qout[n * P_DIM + t] = s;
    }
}

extern "C" void kernel_launch(void* const* d_in, const int* in_sizes, int n_in,
                              void* d_out, int out_size, void* d_ws, size_t ws_size,
                              hipStream_t stream) {
    const float* x  = (const float*)d_in[0];  // [256,16]
    const int*   ei = (const int*)d_in[1];    // [2,32768]
    const float* W  = (const float*)d_in[2];  // [16,2048]
    const float* b  = (const float*)d_in[3];  // [2048]
    const float* Wq = (const float*)d_in[4];  // [256,2048,16]
    const float* bq = (const float*)d_in[5];  // [256,16]
    float* qout = (float*)d_out;              // [256,16]

    float* cnt = (float*)d_ws;                // 65536 floats (dst-major)
    float* deg = cnt + N_NODES * N_NODES;     // 256 floats

    hipMemsetAsync(d_ws, 0, (N_NODES * N_NODES + N_NODES) * sizeof(float), stream);
    k_cnt <<<E_EDGES / 256, 256, 0, stream>>>(ei, cnt, deg);
    k_node<<<N_NODES, BLK, 0, stream>>>(cnt, deg, x, W, b, Wq, bq, qout);
}

// Round 2
// 95.629 us; speedup vs baseline: 1.1637x; 1.1501x over previous
//
#include <hip/hip_runtime.h>

#define N_NODES 256
#define F_DIM   16
#define H_DIM   2048
#define P_DIM   16
#define E_EDGES 32768
#define BLK     512
#define NW      (BLK / 64)

// ---------------------------------------------------------------------------
// Single fused kernel, zero workspace. Algebra (re-associated GCN):
//   g[n][f] = dinv[n] * sum_s (cnt[n][s] + [s==n]) * dinv[s] * x[s][f]
//   o[n][h] = sum_f g[n][f] W[f][h] + b[h]
//   q[n][p] = sum_h o[n][h] Wq[n][h][p] + bq[n][p],  dinv = rsqrt(indeg+1)
// Each block (node n) rebuilds the FULL degree histogram + its own count row
// from the raw edge list in LDS (32768 edges, per-wave histograms), fully
// overlapped with the irreducible 128 KB/block Wq HBM stream (interleaved
// 1 float4 Wq load per edge-scan iteration). No memset, no k_cnt, no global
// roundtrip, no inter-kernel serialization.
// ---------------------------------------------------------------------------
__global__ __launch_bounds__(BLK) void k_fused(
    const int* __restrict__ ei,   const float* __restrict__ x,
    const float* __restrict__ W,  const float* __restrict__ b,
    const float* __restrict__ Wq, const float* __restrict__ bq,
    float* __restrict__ qout)
{
    __shared__ unsigned histw[NW][N_NODES];   // per-wave degree histograms
    __shared__ unsigned cntrow[N_NODES];      // cnt[n][s] for this block's n
    __shared__ float    dinv[N_NODES];
    __shared__ float    gw[4][F_DIM];
    __shared__ float    gfin[F_DIM];
    __shared__ float    red[NW][P_DIM];

    const int n = blockIdx.x;
    const int t = threadIdx.x;
    const int w = t >> 6, l = t & 63;

    // zero LDS histograms (2048 + 256 words over 512 threads)
#pragma unroll
    for (int i = 0; i < 4; ++i) ((unsigned*)histw)[t + i * BLK] = 0u;
    if (t < N_NODES) cntrow[t] = 0u;
    __syncthreads();

    // ---- edge scan (4 edges/thread/iter, int4 coalesced) interleaved with
    //      the Wq stream: one float4 Wq load per iteration keeps both the
    //      L3 edge stream and the HBM Wq stream in flight together.
    const float4* Wqn = (const float4*)(Wq + (size_t)n * (H_DIM * P_DIM));
    float4 u[16];
#pragma unroll
    for (int k = 0; k < 16; ++k) {
        const int base = (k << 11) + (t << 2);          // k*2048 + t*4
        int4 s4 = *(const int4*)(ei + base);
        int4 d4 = *(const int4*)(ei + E_EDGES + base);
        u[k] = Wqn[(t + ((k >> 2) * BLK)) * 4 + (k & 3)];  // row t+512i, word j
        atomicAdd(&histw[w][d4.x], 1u);
        atomicAdd(&histw[w][d4.y], 1u);
        atomicAdd(&histw[w][d4.z], 1u);
        atomicAdd(&histw[w][d4.w], 1u);
        if (d4.x == n) atomicAdd(&cntrow[s4.x], 1u);
        if (d4.y == n) atomicAdd(&cntrow[s4.y], 1u);
        if (d4.z == n) atomicAdd(&cntrow[s4.z], 1u);
        if (d4.w == n) atomicAdd(&cntrow[s4.w], 1u);
    }
    __syncthreads();

    // ---- deg -> dinv (self-loop folded as +1)
    if (t < N_NODES) {
        unsigned dg = 0;
#pragma unroll
        for (int i = 0; i < NW; ++i) dg += histw[i][t];
        dinv[t] = rsqrtf((float)dg + 1.0f);
    }
    __syncthreads();

    // ---- g-phase: waves 0..3, thread t owns source s=t, register butterfly
    if (t < N_NODES) {
        float a = ((float)cntrow[t] + (t == n ? 1.0f : 0.0f)) * dinv[t];
        const float4* x4 = (const float4*)(x + t * F_DIM);
        float4 a0 = x4[0], a1 = x4[1], a2 = x4[2], a3 = x4[3];
        float val[F_DIM];
        val[0]  = a * a0.x; val[1]  = a * a0.y; val[2]  = a * a0.z; val[3]  = a * a0.w;
        val[4]  = a * a1.x; val[5]  = a * a1.y; val[6]  = a * a1.z; val[7]  = a * a1.w;
        val[8]  = a * a2.x; val[9]  = a * a2.y; val[10] = a * a2.z; val[11] = a * a2.w;
        val[12] = a * a3.x; val[13] = a * a3.y; val[14] = a * a3.z; val[15] = a * a3.w;
#pragma unroll
        for (int f = 0; f < F_DIM; ++f)
#pragma unroll
            for (int off = 32; off > 0; off >>= 1)
                val[f] += __shfl_xor(val[f], off, 64);
        if (l == 0) {
#pragma unroll
            for (int f = 0; f < F_DIM; ++f) gw[w][f] = val[f];
        }
    }
    __syncthreads();
    if (t < F_DIM)
        gfin[t] = gw[0][t] + gw[1][t] + gw[2][t] + gw[3][t];
    __syncthreads();

    const float dn = dinv[n];
    float gr[F_DIM];
#pragma unroll
    for (int f = 0; f < F_DIM; ++f) gr[f] = gfin[f] * dn;   // LDS broadcast

    // ---- o[i] = b[hh] + sum_f gr[f]*W[f][hh], hh = t + 512*i (coalesced L2)
    float o[4];
#pragma unroll
    for (int i = 0; i < 4; ++i) {
        int hh = t + BLK * i;
        float v = b[hh];
#pragma unroll
        for (int f = 0; f < F_DIM; ++f)
            v += gr[f] * W[f * H_DIM + hh];
        o[i] = v;
    }

    // ---- acc[p] += o * Wq (u registers long since landed)
    float acc[16];
#pragma unroll
    for (int p = 0; p < 16; ++p) acc[p] = 0.0f;

#define ACC4(OV, U0, U1, U2, U3) { float ov = (OV);                            \
    acc[0]  += ov * U0.x; acc[1]  += ov * U0.y; acc[2]  += ov * U0.z; acc[3]  += ov * U0.w; \
    acc[4]  += ov * U1.x; acc[5]  += ov * U1.y; acc[6]  += ov * U1.z; acc[7]  += ov * U1.w; \
    acc[8]  += ov * U2.x; acc[9]  += ov * U2.y; acc[10] += ov * U2.z; acc[11] += ov * U2.w; \
    acc[12] += ov * U3.x; acc[13] += ov * U3.y; acc[14] += ov * U3.z; acc[15] += ov * U3.w; }

    ACC4(o[0], u[0],  u[1],  u[2],  u[3])
    ACC4(o[1], u[4],  u[5],  u[6],  u[7])
    ACC4(o[2], u[8],  u[9],  u[10], u[11])
    ACC4(o[3], u[12], u[13], u[14], u[15])
#undef ACC4

    // ---- wave butterfly then cross-wave via LDS
#pragma unroll
    for (int p = 0; p < 16; ++p)
#pragma unroll
        for (int off = 32; off > 0; off >>= 1)
            acc[p] += __shfl_down(acc[p], off, 64);

    if (l == 0) {
#pragma unroll
        for (int p = 0; p < 16; ++p) red[w][p] = acc[p];
    }
    __syncthreads();
    if (t < P_DIM) {
        float s = bq[n * P_DIM + t];
#pragma unroll
        for (int ww = 0; ww < NW; ++ww) s += red[ww][t];
        qout[n * P_DIM + t] = s;
    }
}

extern "C" void kernel_launch(void* const* d_in, const int* in_sizes, int n_in,
                              void* d_out, int out_size, void* d_ws, size_t ws_size,
                              hipStream_t stream) {
    const float* x  = (const float*)d_in[0];  // [256,16]
    const int*   ei = (const int*)d_in[1];    // [2,32768]
    const float* W  = (const float*)d_in[2];  // [16,2048]
    const float* b  = (const float*)d_in[3];  // [2048]
    const float* Wq = (const float*)d_in[4];  // [256,2048,16]
    const float* bq = (const float*)d_in[5];  // [256,16]
    float* qout = (float*)d_out;              // [256,16]

    (void)d_ws; (void)ws_size;                // workspace unused: single launch
    k_fused<<<N_NODES, BLK, 0, stream>>>(ei, x, W, b, Wq, bq, qout);
}